// Round 10
// baseline (259.569 us; speedup 1.0000x reference)
//
#include <hip/hip_runtime.h>

// 3-layer GraphConv (PyG) + softmax, 100k nodes, 1.6M edges, f32 in/out.
// R2: pull-gather beats scattered atomics. R9: deterministic 5-kernel build.
// R10/R13/R14: gather staging/bytes/line-req ~null. R11: fp16 fails accuracy.
// R12: int16 row-scaled passes. R15: LDS-atomic gather DISASTER.
// R16: launch merging REGRESSED. R17: group scales + compact rows: 234.7 BEST.
// R18: fused gather+linear via register butterfly: SPILLED (VGPR 40, FETCH
//      61.5MB vs 27 legit) -> 270us. Idea right, implementation wrong.
// R19: 4-serial-node batching: REGRESSED +16us (thread count/MLP dropped 4x).
// R20: R18 fusion via LDS hand-off: gather phase (R17 loop, byte-identical)
//      -> relu'd row to accs[32][34] LDS -> remap (node,f): each thread
//      computes ONE rel + ONE root output (2 accs, no spill), weights in
//      LDS (broadcast/bank-clean). Deletes h1-full write + 2x read (38.4MB)
//      + the 2-pass linear_qg<32,16>. Scale group 32 nodes (gs2[s>>5]).

#define RNODES 128
#define NB_MAX 1024
#define CH 4096            // edges per chunk
#define CMAX 512           // max chunks (scan_chunkhist: one chunk/thread)

// ================= device bodies for the linear ============================
template <int Fin, int Fout, bool RELU>
__device__ __forceinline__ void lin_compute(const float* __restrict__ x,
                                            const float* __restrict__ W,
                                            int n, float* o) {
#pragma unroll
    for (int f = 0; f < Fout; ++f) o[f] = 0.f;
    const float* xr = x + (size_t)n * Fin;
#pragma unroll
    for (int k = 0; k < Fin; k += 4) {
        float4 v = *(const float4*)(xr + k);
        if (RELU) {
            v.x = fmaxf(v.x, 0.f); v.y = fmaxf(v.y, 0.f);
            v.z = fmaxf(v.z, 0.f); v.w = fmaxf(v.w, 0.f);
        }
        const float xv[4] = {v.x, v.y, v.z, v.w};
#pragma unroll
        for (int kk = 0; kk < 4; ++kk) {
            const float* wr = W + (size_t)(k + kk) * Fout;
#pragma unroll
            for (int f = 0; f < Fout; ++f)
                o[f] = fmaf(xv[kk], wr[f], o[f]);
        }
    }
}

// ------- split linear (R17-proven): y=0: t=quant(x@Wrel) int16, per-128-node
//         group scale; y=1: acc=x@Wroot+b (f32). blockDim MUST be 256.
template <int Fin, int Fout, bool RELU>
__global__ void linear_qg_kernel(const float* __restrict__ x,
                                 const float* __restrict__ Wrel,
                                 const float* __restrict__ Wroot,
                                 const float* __restrict__ bias,
                                 short* __restrict__ t,
                                 float* __restrict__ gscale,
                                 float* __restrict__ acc, int N) {
    int n = blockIdx.x * blockDim.x + threadIdx.x;
    const bool valid = (n < N);
    float o[Fout];

    if (blockIdx.y != 0) {
        if (!valid) return;
        lin_compute<Fin, Fout, RELU>(x, Wroot, n, o);
#pragma unroll
        for (int f = 0; f < Fout; ++f) o[f] += bias[f];
        float* arow = acc + (size_t)n * Fout;
        if constexpr (Fout >= 4) {
#pragma unroll
            for (int f = 0; f < Fout; f += 4)
                *(float4*)(arow + f) = make_float4(o[f], o[f+1], o[f+2], o[f+3]);
        } else {
            *(float2*)arow = make_float2(o[0], o[1]);
        }
        return;
    }

    // --- rel path: compute, group-max reduce, quantize compact ---
    float m = 0.f;
    if (valid) {
        lin_compute<Fin, Fout, RELU>(x, Wrel, n, o);
#pragma unroll
        for (int f = 0; f < Fout; ++f) m = fmaxf(m, fabsf(o[f]));
    }
    float wm = m;
#pragma unroll
    for (int off = 1; off < 64; off <<= 1)
        wm = fmaxf(wm, __shfl_xor(wm, off, 64));
    __shared__ float wmax[4];
    const int wv = threadIdx.x >> 6;            // wave id 0..3
    if ((threadIdx.x & 63) == 0) wmax[wv] = wm;
    __syncthreads();
    const float g = fmaxf(wmax[wv & 2], wmax[(wv & 2) | 1]);   // 128-node group
    if (!valid) return;
    const float inv = (g > 0.f) ? (32767.0f / g) : 0.f;
    if ((threadIdx.x & 127) == 0) gscale[n >> 7] = g * (1.0f / 32767.0f);

    short q[Fout];
#pragma unroll
    for (int f = 0; f < Fout; ++f) q[f] = (short)__float2int_rn(o[f] * inv);

    if constexpr (Fout == 32) {
        short* trow = t + (size_t)n * 32;           // 64B compact rows
#pragma unroll
        for (int f = 0; f < 32; f += 8)
            *(int4*)(trow + f) = *(const int4*)(q + f);
    } else if constexpr (Fout == 16) {
        short* trow = t + (size_t)n * 16;           // 32B compact rows
        *(int4*)(trow)     = *(const int4*)(q);
        *(int4*)(trow + 8) = *(const int4*)(q + 8);
    } else {
        ((int*)t)[n] = (int)(unsigned short)q[0] | ((int)q[1] << 16);  // 4B rows
    }
}

// ---------------- build step 1: per-chunk LDS histogram --------------------
__global__ void hist_chunked_kernel(const int* __restrict__ dst,
                                    int* __restrict__ chunkhist,
                                    int nE, int NB) {
    __shared__ int h[NB_MAX];
    const int c  = blockIdx.x;
    const int e0 = c * CH, e1 = min(e0 + CH, nE);
    for (int b = threadIdx.x; b < NB; b += blockDim.x) h[b] = 0;
    __syncthreads();
    for (int e = e0 + threadIdx.x; e < e1; e += blockDim.x)
        atomicAdd(&h[dst[e] >> 7], 1);
    __syncthreads();
    for (int b = threadIdx.x; b < NB; b += blockDim.x)
        chunkhist[(size_t)c * NB + b] = h[b];          // contiguous row flush
}

// ---------------- build step 2: column scan (per bucket over chunks) -------
__global__ void scan_chunkhist_kernel(int* __restrict__ chunkhist,
                                      int* __restrict__ gtotal,
                                      int C, int NB) {
    __shared__ int s[CMAX];
    const int b = blockIdx.x;
    const int t = threadIdx.x;
    int v = (t < C) ? chunkhist[(size_t)t * NB + b] : 0;
    s[t] = v;
    __syncthreads();
    for (int off = 1; off < CMAX; off <<= 1) {
        int u = (t >= off) ? s[t - off] : 0;
        __syncthreads();
        s[t] += u;
        __syncthreads();
    }
    if (t < C) chunkhist[(size_t)t * NB + b] = s[t] - v;   // exclusive
    if (t == CMAX - 1) gtotal[b] = s[t];                   // inclusive total
}

// ---------------- build step 3: bucket scan (single block) -----------------
__global__ void scan_buckets_kernel(const int* __restrict__ gtotal,
                                    int* __restrict__ bptr, int NB, int nE) {
    __shared__ int s[NB_MAX];
    int t = threadIdx.x;
    int own = (t < NB) ? gtotal[t] : 0;
    s[t] = own;
    __syncthreads();
    for (int off = 1; off < NB_MAX; off <<= 1) {
        int v = (t >= off) ? s[t - off] : 0;
        __syncthreads();
        s[t] += v;
        __syncthreads();
    }
    if (t < NB) bptr[t] = s[t] - own;
    if (t == 0) bptr[NB] = nE;
}

// ---------------- build step 4: deterministic placement --------------------
__global__ void bucketize_det_kernel(const int* __restrict__ src,
                                     const int* __restrict__ dst,
                                     const int* __restrict__ chunkpre,
                                     const int* __restrict__ bptr,
                                     unsigned int* __restrict__ records,
                                     int nE, int NB) {
    __shared__ int lcur[NB_MAX];
    const int c  = blockIdx.x;
    const int e0 = c * CH, e1 = min(e0 + CH, nE);
    for (int b = threadIdx.x; b < NB; b += blockDim.x)
        lcur[b] = bptr[b] + chunkpre[(size_t)c * NB + b];
    __syncthreads();
    for (int e = e0 + threadIdx.x; e < e1; e += blockDim.x) {
        int d = dst[e];
        int b = d >> 7;
        int pos = atomicAdd(&lcur[b], 1);                  // LDS-only atomic
        records[pos] = (unsigned int)src[e] | ((unsigned int)(d & 127) << 17);
    }
}

// ---------------- build step 5: per-bucket hist+scan+rowptr+place ----------
__global__ void place_merge_kernel(const unsigned int* __restrict__ records,
                                   const int* __restrict__ bptr,
                                   int* __restrict__ rowptr,
                                   int* __restrict__ srcs_sorted,
                                   int N, int nE, int NB) {
    __shared__ int hist[RNODES];
    __shared__ int s[RNODES];
    __shared__ int lcur[RNODES];
    const int b    = blockIdx.x;
    const int base = b * RNODES;
    const int nn   = min(RNODES, N - base);
    const int beg  = bptr[b], end = bptr[b + 1];
    const int t    = threadIdx.x;

    if (t < RNODES) hist[t] = 0;
    __syncthreads();
    for (int i = beg + t; i < end; i += blockDim.x)
        atomicAdd(&hist[records[i] >> 17], 1);
    __syncthreads();

    if (t < RNODES) s[t] = hist[t];
    __syncthreads();
    for (int off = 1; off < RNODES; off <<= 1) {
        int v = (t < RNODES && t >= off) ? s[t - off] : 0;
        __syncthreads();
        if (t < RNODES && t >= off) s[t] += v;
        __syncthreads();
    }
    if (t < nn) {
        int ex = beg + s[t] - hist[t];
        rowptr[base + t] = ex;
        lcur[t] = ex;
    }
    if (b == NB - 1 && t == 0) rowptr[N] = nE;
    __syncthreads();

    for (int i = beg + t; i < end; i += blockDim.x) {
        unsigned int rec = records[i];
        int pos = atomicAdd(&lcur[rec >> 17], 1);
        srcs_sorted[pos] = (int)(rec & 0x1FFFFu);
    }
}

// ====== FUSED gather32 + linear2 via LDS (R18 idea, spill-free) ============
// 512 thr = 32 nodes x 16 lanes. Phase 1: R17 gather loop -> relu'd row to
// accs[32][34] (padded). Phase 2: remap (node,f): 1 rel + 1 root acc per
// thread; weights in LDS. Scale group = 32 nodes -> gs2[blockIdx.x].
__global__ void g32lin2_kernel(const short* __restrict__ t1,
                               const float* __restrict__ gs1,
                               const int* __restrict__ rowptr,
                               const int* __restrict__ srcs,
                               const float* __restrict__ h1root,
                               const float* __restrict__ Wrel2,
                               const float* __restrict__ Wroot2,
                               const float* __restrict__ b2,
                               short* __restrict__ t2,
                               float* __restrict__ gs2,
                               float* __restrict__ h2root,
                               int N) {
    __shared__ float accs[32 * 34];             // padded rows: bank-clean
    __shared__ float Wr[512], Wo[512];          // 32x16 each
    __shared__ float wmax[8];
    const int tid = threadIdx.x;
    Wr[tid] = Wrel2[tid];
    Wo[tid] = Wroot2[tid];

    const int nl = tid >> 4;                    // node local 0..31
    const int fp = tid & 15;
    const int n  = blockIdx.x * 32 + nl;
    const bool valid = (n < N);

    // ---- phase 1: gather (R17-proven loop) ----
    float sx = 0.f, sy = 0.f;
    if (valid) {
        const int* tp = (const int*)t1;         // 16 ints/row (64B)
        int beg = rowptr[n], end = rowptr[n + 1];
        int e = beg;
        for (; e + 8 <= end; e += 8) {
            int s[8];
#pragma unroll
            for (int u = 0; u < 8; ++u) s[u] = srcs[e + u];
            int q[8]; float sc[8];
#pragma unroll
            for (int u = 0; u < 8; ++u) {
                q[u]  = tp[(size_t)s[u] * 16 + fp];
                sc[u] = gs1[s[u] >> 7];         // 3KB: L1-hit
            }
#pragma unroll
            for (int u = 0; u < 8; ++u) {
                sx = fmaf(sc[u], (float)((short)(q[u] & 0xFFFF)), sx);
                sy = fmaf(sc[u], (float)(q[u] >> 16), sy);
            }
        }
        for (; e < end; ++e) {
            int s0 = srcs[e];
            int qv = tp[(size_t)s0 * 16 + fp];
            float sc = gs1[s0 >> 7];
            sx = fmaf(sc, (float)((short)(qv & 0xFFFF)), sx);
            sy = fmaf(sc, (float)(qv >> 16), sy);
        }
        const float2 r0 = *(const float2*)(h1root + (size_t)n * 32 + 2 * fp);
        sx += r0.x; sy += r0.y;
    }
    // relu'd layer-2 input (zeros for invalid nodes -> safe block max)
    accs[nl * 34 + 2 * fp]     = valid ? fmaxf(sx, 0.f) : 0.f;
    accs[nl * 34 + 2 * fp + 1] = valid ? fmaxf(sy, 0.f) : 0.f;
    __syncthreads();

    // ---- phase 2: linear (node=nl, output f=fp): 2 accumulators ----
    float orel = 0.f, oroot = 0.f;
    const float* arow = accs + nl * 34;
#pragma unroll
    for (int k = 0; k < 32; ++k) {
        const float a = arow[k];                // broadcast within node
        orel  = fmaf(a, Wr[k * 16 + fp], orel);
        oroot = fmaf(a, Wo[k * 16 + fp], oroot);
    }

    // ---- block max of |orel| over 512 threads (32-node scale group) ----
    float m = fabsf(orel);
#pragma unroll
    for (int off = 1; off < 64; off <<= 1)
        m = fmaxf(m, __shfl_xor(m, off, 64));
    if ((tid & 63) == 0) wmax[tid >> 6] = m;
    __syncthreads();
    float g = wmax[0];
#pragma unroll
    for (int w = 1; w < 8; ++w) g = fmaxf(g, wmax[w]);
    const float inv = (g > 0.f) ? (32767.0f / g) : 0.f;
    if (tid == 0) gs2[blockIdx.x] = g * (1.0f / 32767.0f);

    if (!valid) return;
    t2[(size_t)n * 16 + fp] = (short)__float2int_rn(orel * inv);
    h2root[(size_t)n * 16 + fp] = oroot + b2[fp];
}

// ------- L2 gather (R17): 32B rows, gs2 per-32-node (>>5); 8 lanes/node ----
__global__ void gather16_g_kernel(const short* __restrict__ t,
                                  const float* __restrict__ gscale,
                                  const int* __restrict__ rowptr,
                                  const int* __restrict__ srcs,
                                  const float* __restrict__ rootacc,
                                  float* __restrict__ out, int N) {
    int tid = blockIdx.x * blockDim.x + threadIdx.x;
    int n  = tid >> 3;
    int fp = tid & 7;
    if (n >= N) return;

    const int* tp = (const int*)t;              // 8 ints per row (32B)
    int beg = rowptr[n], end = rowptr[n + 1];
    float sx = 0.f, sy = 0.f;
    int e = beg;
    for (; e + 8 <= end; e += 8) {
        int s[8];
#pragma unroll
        for (int u = 0; u < 8; ++u) s[u] = srcs[e + u];
        int q[8]; float sc[8];
#pragma unroll
        for (int u = 0; u < 8; ++u) {
            q[u]  = tp[(size_t)s[u] * 8 + fp];
            sc[u] = gscale[s[u] >> 5];          // per-32-node (12.5KB)
        }
#pragma unroll
        for (int u = 0; u < 8; ++u) {
            sx = fmaf(sc[u], (float)((short)(q[u] & 0xFFFF)), sx);
            sy = fmaf(sc[u], (float)(q[u] >> 16), sy);
        }
    }
    for (; e < end; ++e) {
        int s0 = srcs[e];
        int qv = tp[(size_t)s0 * 8 + fp];
        float sc = gscale[s0 >> 5];
        sx = fmaf(sc, (float)((short)(qv & 0xFFFF)), sx);
        sy = fmaf(sc, (float)(qv >> 16), sy);
    }

    const float2 r0 = *(const float2*)(rootacc + (size_t)n * 16 + 2 * fp);
    *(float2*)(out + (size_t)n * 16 + 2 * fp) = make_float2(r0.x + sx, r0.y + sy);
}

// ------- L3 gather (R17): 4B rows + per-128 group scale, 4 lanes/node ------
__global__ void gather2_g_kernel(const short* __restrict__ t,
                                 const float* __restrict__ gscale,
                                 const int* __restrict__ rowptr,
                                 const int* __restrict__ srcs,
                                 const float* __restrict__ rootacc,
                                 float* __restrict__ out, int N) {
    int tid = blockIdx.x * blockDim.x + threadIdx.x;
    int n  = tid >> 2;
    int fp = tid & 3;
    if (n >= N) return;

    const int* tp = (const int*)t;              // 4B rows (packed short2)
    int beg = rowptr[n], end = rowptr[n + 1];
    float sx = 0.f, sy = 0.f;
    int e = beg + fp;
    for (; e + 12 < end; e += 16) {
        int s0 = srcs[e], s1 = srcs[e + 4], s2 = srcs[e + 8], s3 = srcs[e + 12];
        int r0 = tp[s0], r1 = tp[s1], r2 = tp[s2], r3 = tp[s3];
        float c0 = gscale[s0 >> 7], c1 = gscale[s1 >> 7];
        float c2 = gscale[s2 >> 7], c3 = gscale[s3 >> 7];
        sx = fmaf(c0, (float)((short)(r0 & 0xFFFF)), sx);
        sy = fmaf(c0, (float)(r0 >> 16), sy);
        sx = fmaf(c1, (float)((short)(r1 & 0xFFFF)), sx);
        sy = fmaf(c1, (float)(r1 >> 16), sy);
        sx = fmaf(c2, (float)((short)(r2 & 0xFFFF)), sx);
        sy = fmaf(c2, (float)(r2 >> 16), sy);
        sx = fmaf(c3, (float)((short)(r3 & 0xFFFF)), sx);
        sy = fmaf(c3, (float)(r3 >> 16), sy);
    }
    for (; e < end; e += 4) {
        int s0 = srcs[e];
        int r = tp[s0];
        float c = gscale[s0 >> 7];
        sx = fmaf(c, (float)((short)(r & 0xFFFF)), sx);
        sy = fmaf(c, (float)(r >> 16), sy);
    }
    sx += __shfl_xor(sx, 1, 64); sy += __shfl_xor(sy, 1, 64);
    sx += __shfl_xor(sx, 2, 64); sy += __shfl_xor(sy, 2, 64);

    if (fp == 0) {
        const float2 r0 = *(const float2*)(rootacc + (size_t)n * 2);
        float a = r0.x + sx, b = r0.y + sy;
        float m = fmaxf(a, b);
        float ea = __expf(a - m), eb = __expf(b - m);
        float inv = 1.0f / (ea + eb);
        *(float2*)(out + (size_t)n * 2) = make_float2(ea * inv, eb * inv);
    }
}

// ---------------- fallback (R2 atomic path) --------------------------------
template <int Fin, int Fout, bool RELU>
__global__ void linear2_kernel(const float* __restrict__ x,
                               const float* __restrict__ Wrel,
                               const float* __restrict__ Wroot,
                               const float* __restrict__ bias,
                               float* __restrict__ t,
                               float* __restrict__ acc, int N) {
    const bool rootTask = (blockIdx.y != 0);
    const float* __restrict__ W = rootTask ? Wroot : Wrel;
    float* __restrict__ outp    = rootTask ? acc : t;

    int n = blockIdx.x * blockDim.x + threadIdx.x;
    if (n >= N) return;

    float o[Fout];
    lin_compute<Fin, Fout, RELU>(x, W, n, o);
    if (rootTask) {
#pragma unroll
        for (int f = 0; f < Fout; ++f) o[f] += bias[f];
    }
    float* op = outp + (size_t)n * Fout;
    if constexpr (Fout >= 4) {
#pragma unroll
        for (int f = 0; f < Fout; f += 4)
            *(float4*)(op + f) = make_float4(o[f], o[f + 1], o[f + 2], o[f + 3]);
    } else {
        *(float2*)op = make_float2(o[0], o[1]);
    }
}

template <int F>
__global__ void scatter_kernel(const float* __restrict__ t,
                               const int* __restrict__ src,
                               const int* __restrict__ dst,
                               float* __restrict__ acc, int nE) {
    int tid = blockIdx.x * blockDim.x + threadIdx.x;
    int e = tid / F;
    if (e >= nE) return;
    int f = tid & (F - 1);
    atomicAdd(acc + (long)dst[e] * F + f, t[(long)src[e] * F + f]);
}

__global__ void softmax2_kernel(const float* __restrict__ h, float* __restrict__ out, int N) {
    int n = blockIdx.x * blockDim.x + threadIdx.x;
    if (n >= N) return;
    float a = h[2 * n], b = h[2 * n + 1];
    float m = fmaxf(a, b);
    float ea = __expf(a - m), eb = __expf(b - m);
    float inv = 1.0f / (ea + eb);
    out[2 * n] = ea * inv;
    out[2 * n + 1] = eb * inv;
}

extern "C" void kernel_launch(void* const* d_in, const int* in_sizes, int n_in,
                              void* d_out, int out_size, void* d_ws, size_t ws_size,
                              hipStream_t stream) {
    const float* z      = (const float*)d_in[0];
    const int*   ei     = (const int*)d_in[1];
    const float* Wrel1  = (const float*)d_in[2];
    const float* Wroot1 = (const float*)d_in[3];
    const float* b1     = (const float*)d_in[4];
    const float* Wrel2  = (const float*)d_in[5];
    const float* Wroot2 = (const float*)d_in[6];
    const float* b2     = (const float*)d_in[7];
    const float* Wrel3  = (const float*)d_in[8];
    const float* Wroot3 = (const float*)d_in[9];
    const float* b3     = (const float*)d_in[10];

    const int N  = in_sizes[0] / 64;   // 100000
    const int nE = in_sizes[1] / 2;    // 1600000
    const int* src = ei;
    const int* dst = ei + nE;
    const int NB = (N + RNODES - 1) / RNODES;   // 782
    const int C  = (nE + CH - 1) / CH;          // 391 chunks
    const int G32 = (N + 31) / 32;              // fused blocks / gs2 size

    // ---- flat workspace layout (no aliasing) ----
    char* wsb = (char*)d_ws;
    size_t off = 0;
    auto take = [&](size_t bytes) -> void* {
        void* p = (void*)(wsb + off);
        off = (off + bytes + 255) & ~(size_t)255;
        return p;
    };
    int*          chunkhist   = (int*)take((size_t)CMAX * NB_MAX * 4);
    int*          gtotal      = (int*)take((size_t)NB_MAX * 4);
    int*          bptr        = (int*)take((size_t)(NB_MAX + 1) * 4);
    unsigned int* records     = (unsigned int*)take((size_t)nE * 4);
    int*          rowptr      = (int*)take((size_t)(N + 1) * 4);
    int*          srcs_sorted = (int*)take((size_t)nE * 4);
    short*        t1          = (short*)take((size_t)N * 32 * 2);   // 64B rows
    float*        gs1         = (float*)take((size_t)NB_MAX * 4);   // per-128
    float*        h1          = (float*)take((size_t)N * 32 * 4);   // root acc
    short*        t2          = (short*)take((size_t)N * 16 * 2);   // 32B rows
    float*        gs2         = (float*)take((size_t)G32 * 4);      // per-32
    float*        h2          = (float*)take((size_t)N * 16 * 4);   // root acc
    short*        t3          = (short*)take((size_t)N * 2 * 2);    // 4B rows
    float*        gs3         = (float*)take((size_t)NB_MAX * 4);   // per-128
    float*        h3          = (float*)take((size_t)N * 2 * 4);
    const size_t needed = off;

    const int B = 256;
    const int nodeBlocks = (N + B - 1) / B;
    const dim3 linGrid(nodeBlocks, 2);       // y=0: rel(quant)->t, y=1: root+b->acc
    const bool packOK = (N <= (1 << 17)) && (NB <= NB_MAX) && (C <= CMAX);

    if (ws_size >= needed && packOK) {
        // ---- build: zero-global-atomic deterministic CSR (R14-proven) ----
        hist_chunked_kernel<<<C, 512, 0, stream>>>(dst, chunkhist, nE, NB);
        scan_chunkhist_kernel<<<NB, CMAX, 0, stream>>>(chunkhist, gtotal, C, NB);
        scan_buckets_kernel<<<1, NB_MAX, 0, stream>>>(gtotal, bptr, NB, nE);
        bucketize_det_kernel<<<C, 512, 0, stream>>>(src, dst, chunkhist, bptr, records, nE, NB);
        place_merge_kernel<<<NB, 512, 0, stream>>>(records, bptr, rowptr, srcs_sorted, N, nE, NB);

        // ---- Layer 1: 64 -> 32 (split linear, R17-proven) ----
        linear_qg_kernel<64, 32, false><<<linGrid, B, 0, stream>>>(
            z, Wrel1, Wroot1, b1, t1, gs1, h1, N);

        // ---- FUSED: gather32 + ReLU + linear2 (LDS hand-off) ----
        g32lin2_kernel<<<G32, 512, 0, stream>>>(
            t1, gs1, rowptr, srcs_sorted, h1, Wrel2, Wroot2, b2, t2, gs2, h2, N);

        // ---- Layer 2 gather (32B rows, L2-resident) ----
        gather16_g_kernel<<<((size_t)N * 8 + B - 1) / B, B, 0, stream>>>(
            t2, gs2, rowptr, srcs_sorted, h2, h2, N);

        // ---- Layer 3: 16 -> 2, then gather2 + softmax ----
        linear_qg_kernel<16, 2, true><<<linGrid, B, 0, stream>>>(
            h2, Wrel3, Wroot3, b3, t3, gs3, h3, N);
        gather2_g_kernel<<<((size_t)N * 4 + B - 1) / B, B, 0, stream>>>(
            t3, gs3, rowptr, srcs_sorted, h3, (float*)d_out, N);
    } else {
        // ---- fallback: R2 atomic-scatter path (all f32, ping-pong layout) ----
        float* regionA = (float*)d_ws;
        float* regionB = regionA + (size_t)N * 32;
        float* ft1 = regionA;
        float* fh1 = regionB;
        float* ft2 = regionA;
        float* fh2 = regionA + (size_t)N * 16;
        float* ft3 = regionB;
        float* fh3 = regionB + (size_t)N * 2;
        linear2_kernel<64, 32, false><<<linGrid, B, 0, stream>>>(z, Wrel1, Wroot1, b1, ft1, fh1, N);
        scatter_kernel<32><<<((size_t)nE * 32 + B - 1) / B, B, 0, stream>>>(ft1, src, dst, fh1, nE);
        linear2_kernel<32, 16, true><<<linGrid, B, 0, stream>>>(fh1, Wrel2, Wroot2, b2, ft2, fh2, N);
        scatter_kernel<16><<<((size_t)nE * 16 + B - 1) / B, B, 0, stream>>>(ft2, src, dst, fh2, nE);
        linear2_kernel<16, 2, true><<<linGrid, B, 0, stream>>>(fh2, Wrel3, Wroot3, b3, ft3, fh3, N);
        scatter_kernel<2><<<((size_t)nE * 2 + B - 1) / B, B, 0, stream>>>(ft3, src, dst, fh3, nE);
        softmax2_kernel<<<nodeBlocks, B, 0, stream>>>(fh3, (float*)d_out, N);
    }
}

// Round 11
// 234.805 us; speedup vs baseline: 1.1055x; 1.1055x over previous
//
#include <hip/hip_runtime.h>

// 3-layer GraphConv (PyG) + softmax, 100k nodes, 1.6M edges, f32 in/out.
// R2: pull-gather beats scattered atomics. R9: deterministic 5-kernel build.
// R10/R13/R14: gather staging/bytes/line-req ~null. R11: fp16 fails accuracy.
// R12: int16 row-scaled passes. R15: LDS-atomic gather DISASTER.
// R16: launch merging REGRESSED. R17: group scales + compact rows: 234.7 BEST.
// R18/R20: fusion via registers (spill) and via LDS (block-level degree sync,
//      occupancy 36%) BOTH slower. R20's counters falsified R18's spill read:
//      FETCH ~61MB is gather32's legitimate L2-miss traffic (6.4MB t1 > 4MB
//      per-XCD L2, L3-absorbed). Fusion = 3x-confirmed dead end.
// R19: 4-serial-node batching REGRESSED (thread count/MLP dropped 4x).
// R21: R17 EXACTLY + build tuning only: CH 4096->8192 (C=196), CMAX 256,
//      place_merge at 1024 threads. Last untouched dial; if <3us, declare
//      structural floor (~72G req/s random-access ceiling).

#define RNODES 128
#define NB_MAX 1024
#define CH 8192            // edges per chunk (R21: was 4096)
#define CMAX 256           // max chunks (R21: was 512; C=196 fits)

// ================= device bodies for the linear ============================
template <int Fin, int Fout, bool RELU>
__device__ __forceinline__ void lin_compute(const float* __restrict__ x,
                                            const float* __restrict__ W,
                                            int n, float* o) {
#pragma unroll
    for (int f = 0; f < Fout; ++f) o[f] = 0.f;
    const float* xr = x + (size_t)n * Fin;
#pragma unroll
    for (int k = 0; k < Fin; k += 4) {
        float4 v = *(const float4*)(xr + k);
        if (RELU) {
            v.x = fmaxf(v.x, 0.f); v.y = fmaxf(v.y, 0.f);
            v.z = fmaxf(v.z, 0.f); v.w = fmaxf(v.w, 0.f);
        }
        const float xv[4] = {v.x, v.y, v.z, v.w};
#pragma unroll
        for (int kk = 0; kk < 4; ++kk) {
            const float* wr = W + (size_t)(k + kk) * Fout;
#pragma unroll
            for (int f = 0; f < Fout; ++f)
                o[f] = fmaf(xv[kk], wr[f], o[f]);
        }
    }
}

// ------- split linear (R17-proven): y=0: t=quant(x@Wrel) int16, per-128-node
//         group scale; y=1: acc=x@Wroot+b (f32). blockDim MUST be 256.
template <int Fin, int Fout, bool RELU>
__global__ void linear_qg_kernel(const float* __restrict__ x,
                                 const float* __restrict__ Wrel,
                                 const float* __restrict__ Wroot,
                                 const float* __restrict__ bias,
                                 short* __restrict__ t,
                                 float* __restrict__ gscale,
                                 float* __restrict__ acc, int N) {
    int n = blockIdx.x * blockDim.x + threadIdx.x;
    const bool valid = (n < N);
    float o[Fout];

    if (blockIdx.y != 0) {
        if (!valid) return;
        lin_compute<Fin, Fout, RELU>(x, Wroot, n, o);
#pragma unroll
        for (int f = 0; f < Fout; ++f) o[f] += bias[f];
        float* arow = acc + (size_t)n * Fout;
        if constexpr (Fout >= 4) {
#pragma unroll
            for (int f = 0; f < Fout; f += 4)
                *(float4*)(arow + f) = make_float4(o[f], o[f+1], o[f+2], o[f+3]);
        } else {
            *(float2*)arow = make_float2(o[0], o[1]);
        }
        return;
    }

    // --- rel path: compute, group-max reduce, quantize compact ---
    float m = 0.f;
    if (valid) {
        lin_compute<Fin, Fout, RELU>(x, Wrel, n, o);
#pragma unroll
        for (int f = 0; f < Fout; ++f) m = fmaxf(m, fabsf(o[f]));
    }
    float wm = m;
#pragma unroll
    for (int off = 1; off < 64; off <<= 1)
        wm = fmaxf(wm, __shfl_xor(wm, off, 64));
    __shared__ float wmax[4];
    const int wv = threadIdx.x >> 6;            // wave id 0..3
    if ((threadIdx.x & 63) == 0) wmax[wv] = wm;
    __syncthreads();
    const float g = fmaxf(wmax[wv & 2], wmax[(wv & 2) | 1]);   // 128-node group
    if (!valid) return;
    const float inv = (g > 0.f) ? (32767.0f / g) : 0.f;
    if ((threadIdx.x & 127) == 0) gscale[n >> 7] = g * (1.0f / 32767.0f);

    short q[Fout];
#pragma unroll
    for (int f = 0; f < Fout; ++f) q[f] = (short)__float2int_rn(o[f] * inv);

    if constexpr (Fout == 32) {
        short* trow = t + (size_t)n * 32;           // 64B compact rows
#pragma unroll
        for (int f = 0; f < 32; f += 8)
            *(int4*)(trow + f) = *(const int4*)(q + f);
    } else if constexpr (Fout == 16) {
        short* trow = t + (size_t)n * 16;           // 32B compact rows
        *(int4*)(trow)     = *(const int4*)(q);
        *(int4*)(trow + 8) = *(const int4*)(q + 8);
    } else {
        ((int*)t)[n] = (int)(unsigned short)q[0] | ((int)q[1] << 16);  // 4B rows
    }
}

// ---------------- build step 1: per-chunk LDS histogram --------------------
__global__ void hist_chunked_kernel(const int* __restrict__ dst,
                                    int* __restrict__ chunkhist,
                                    int nE, int NB) {
    __shared__ int h[NB_MAX];
    const int c  = blockIdx.x;
    const int e0 = c * CH, e1 = min(e0 + CH, nE);
    for (int b = threadIdx.x; b < NB; b += blockDim.x) h[b] = 0;
    __syncthreads();
    for (int e = e0 + threadIdx.x; e < e1; e += blockDim.x)
        atomicAdd(&h[dst[e] >> 7], 1);
    __syncthreads();
    for (int b = threadIdx.x; b < NB; b += blockDim.x)
        chunkhist[(size_t)c * NB + b] = h[b];          // contiguous row flush
}

// ---------------- build step 2: column scan (per bucket over chunks) -------
__global__ void scan_chunkhist_kernel(int* __restrict__ chunkhist,
                                      int* __restrict__ gtotal,
                                      int C, int NB) {
    __shared__ int s[CMAX];
    const int b = blockIdx.x;
    const int t = threadIdx.x;
    int v = (t < C) ? chunkhist[(size_t)t * NB + b] : 0;
    s[t] = v;
    __syncthreads();
    for (int off = 1; off < CMAX; off <<= 1) {
        int u = (t >= off) ? s[t - off] : 0;
        __syncthreads();
        s[t] += u;
        __syncthreads();
    }
    if (t < C) chunkhist[(size_t)t * NB + b] = s[t] - v;   // exclusive
    if (t == CMAX - 1) gtotal[b] = s[t];                   // inclusive total
}

// ---------------- build step 3: bucket scan (single block) -----------------
__global__ void scan_buckets_kernel(const int* __restrict__ gtotal,
                                    int* __restrict__ bptr, int NB, int nE) {
    __shared__ int s[NB_MAX];
    int t = threadIdx.x;
    int own = (t < NB) ? gtotal[t] : 0;
    s[t] = own;
    __syncthreads();
    for (int off = 1; off < NB_MAX; off <<= 1) {
        int v = (t >= off) ? s[t - off] : 0;
        __syncthreads();
        s[t] += v;
        __syncthreads();
    }
    if (t < NB) bptr[t] = s[t] - own;
    if (t == 0) bptr[NB] = nE;
}

// ---------------- build step 4: deterministic placement --------------------
__global__ void bucketize_det_kernel(const int* __restrict__ src,
                                     const int* __restrict__ dst,
                                     const int* __restrict__ chunkpre,
                                     const int* __restrict__ bptr,
                                     unsigned int* __restrict__ records,
                                     int nE, int NB) {
    __shared__ int lcur[NB_MAX];
    const int c  = blockIdx.x;
    const int e0 = c * CH, e1 = min(e0 + CH, nE);
    for (int b = threadIdx.x; b < NB; b += blockDim.x)
        lcur[b] = bptr[b] + chunkpre[(size_t)c * NB + b];
    __syncthreads();
    for (int e = e0 + threadIdx.x; e < e1; e += blockDim.x) {
        int d = dst[e];
        int b = d >> 7;
        int pos = atomicAdd(&lcur[b], 1);                  // LDS-only atomic
        records[pos] = (unsigned int)src[e] | ((unsigned int)(d & 127) << 17);
    }
}

// ---------------- build step 5: per-bucket hist+scan+rowptr+place ----------
// R21: launched with 1024 threads (main loops 2 iters/bucket vs 4).
__global__ void place_merge_kernel(const unsigned int* __restrict__ records,
                                   const int* __restrict__ bptr,
                                   int* __restrict__ rowptr,
                                   int* __restrict__ srcs_sorted,
                                   int N, int nE, int NB) {
    __shared__ int hist[RNODES];
    __shared__ int s[RNODES];
    __shared__ int lcur[RNODES];
    const int b    = blockIdx.x;
    const int base = b * RNODES;
    const int nn   = min(RNODES, N - base);
    const int beg  = bptr[b], end = bptr[b + 1];
    const int t    = threadIdx.x;

    if (t < RNODES) hist[t] = 0;
    __syncthreads();
    for (int i = beg + t; i < end; i += blockDim.x)
        atomicAdd(&hist[records[i] >> 17], 1);
    __syncthreads();

    if (t < RNODES) s[t] = hist[t];
    __syncthreads();
    for (int off = 1; off < RNODES; off <<= 1) {
        int v = (t < RNODES && t >= off) ? s[t - off] : 0;
        __syncthreads();
        if (t < RNODES && t >= off) s[t] += v;
        __syncthreads();
    }
    if (t < nn) {
        int ex = beg + s[t] - hist[t];
        rowptr[base + t] = ex;
        lcur[t] = ex;
    }
    if (b == NB - 1 && t == 0) rowptr[N] = nE;
    __syncthreads();

    for (int i = beg + t; i < end; i += blockDim.x) {
        unsigned int rec = records[i];
        int pos = atomicAdd(&lcur[rec >> 17], 1);
        srcs_sorted[pos] = (int)(rec & 0x1FFFFu);
    }
}

// ------- L1 gather: 64B rows + group scale (L1-resident); 16 lanes/node ----
__global__ void gather32_g_kernel(const short* __restrict__ t,
                                  const float* __restrict__ gscale,
                                  const int* __restrict__ rowptr,
                                  const int* __restrict__ srcs,
                                  const float* __restrict__ rootacc,
                                  float* __restrict__ out, int N) {
    int tid = blockIdx.x * blockDim.x + threadIdx.x;
    int n  = tid >> 4;
    int fp = tid & 15;
    if (n >= N) return;

    const int* tp = (const int*)t;              // 16 ints per row (64B)
    int beg = rowptr[n], end = rowptr[n + 1];
    float sx = 0.f, sy = 0.f;
    int e = beg;
    for (; e + 8 <= end; e += 8) {
        int s[8];
#pragma unroll
        for (int u = 0; u < 8; ++u) s[u] = srcs[e + u];
        int q[8]; float sc[8];
#pragma unroll
        for (int u = 0; u < 8; ++u) {
            q[u]  = tp[(size_t)s[u] * 16 + fp];
            sc[u] = gscale[s[u] >> 7];          // 3KB table: L1-hit
        }
#pragma unroll
        for (int u = 0; u < 8; ++u) {
            sx = fmaf(sc[u], (float)((short)(q[u] & 0xFFFF)), sx);
            sy = fmaf(sc[u], (float)(q[u] >> 16), sy);
        }
    }
    for (; e < end; ++e) {
        int s0 = srcs[e];
        int qv = tp[(size_t)s0 * 16 + fp];
        float sc = gscale[s0 >> 7];
        sx = fmaf(sc, (float)((short)(qv & 0xFFFF)), sx);
        sy = fmaf(sc, (float)(qv >> 16), sy);
    }

    const float2 r0 = *(const float2*)(rootacc + (size_t)n * 32 + 2 * fp);
    *(float2*)(out + (size_t)n * 32 + 2 * fp) = make_float2(r0.x + sx, r0.y + sy);
}

// ------- L2 gather: 32B compact rows (3.2MB, L2-resident); 8 lanes/node ----
__global__ void gather16_g_kernel(const short* __restrict__ t,
                                  const float* __restrict__ gscale,
                                  const int* __restrict__ rowptr,
                                  const int* __restrict__ srcs,
                                  const float* __restrict__ rootacc,
                                  float* __restrict__ out, int N) {
    int tid = blockIdx.x * blockDim.x + threadIdx.x;
    int n  = tid >> 3;
    int fp = tid & 7;
    if (n >= N) return;

    const int* tp = (const int*)t;              // 8 ints per row (32B)
    int beg = rowptr[n], end = rowptr[n + 1];
    float sx = 0.f, sy = 0.f;
    int e = beg;
    for (; e + 8 <= end; e += 8) {
        int s[8];
#pragma unroll
        for (int u = 0; u < 8; ++u) s[u] = srcs[e + u];
        int q[8]; float sc[8];
#pragma unroll
        for (int u = 0; u < 8; ++u) {
            q[u]  = tp[(size_t)s[u] * 8 + fp];
            sc[u] = gscale[s[u] >> 7];
        }
#pragma unroll
        for (int u = 0; u < 8; ++u) {
            sx = fmaf(sc[u], (float)((short)(q[u] & 0xFFFF)), sx);
            sy = fmaf(sc[u], (float)(q[u] >> 16), sy);
        }
    }
    for (; e < end; ++e) {
        int s0 = srcs[e];
        int qv = tp[(size_t)s0 * 8 + fp];
        float sc = gscale[s0 >> 7];
        sx = fmaf(sc, (float)((short)(qv & 0xFFFF)), sx);
        sy = fmaf(sc, (float)(qv >> 16), sy);
    }

    const float2 r0 = *(const float2*)(rootacc + (size_t)n * 16 + 2 * fp);
    *(float2*)(out + (size_t)n * 16 + 2 * fp) = make_float2(r0.x + sx, r0.y + sy);
}

// ------- L3 gather: 4B rows (0.4MB) + group scale, 4 lanes/node ------------
__global__ void gather2_g_kernel(const short* __restrict__ t,
                                 const float* __restrict__ gscale,
                                 const int* __restrict__ rowptr,
                                 const int* __restrict__ srcs,
                                 const float* __restrict__ rootacc,
                                 float* __restrict__ out, int N) {
    int tid = blockIdx.x * blockDim.x + threadIdx.x;
    int n  = tid >> 2;
    int fp = tid & 3;
    if (n >= N) return;

    const int* tp = (const int*)t;              // 4B rows (packed short2)
    int beg = rowptr[n], end = rowptr[n + 1];
    float sx = 0.f, sy = 0.f;
    int e = beg + fp;
    for (; e + 12 < end; e += 16) {
        int s0 = srcs[e], s1 = srcs[e + 4], s2 = srcs[e + 8], s3 = srcs[e + 12];
        int r0 = tp[s0], r1 = tp[s1], r2 = tp[s2], r3 = tp[s3];
        float c0 = gscale[s0 >> 7], c1 = gscale[s1 >> 7];
        float c2 = gscale[s2 >> 7], c3 = gscale[s3 >> 7];
        sx = fmaf(c0, (float)((short)(r0 & 0xFFFF)), sx);
        sy = fmaf(c0, (float)(r0 >> 16), sy);
        sx = fmaf(c1, (float)((short)(r1 & 0xFFFF)), sx);
        sy = fmaf(c1, (float)(r1 >> 16), sy);
        sx = fmaf(c2, (float)((short)(r2 & 0xFFFF)), sx);
        sy = fmaf(c2, (float)(r2 >> 16), sy);
        sx = fmaf(c3, (float)((short)(r3 & 0xFFFF)), sx);
        sy = fmaf(c3, (float)(r3 >> 16), sy);
    }
    for (; e < end; e += 4) {
        int s0 = srcs[e];
        int r = tp[s0];
        float c = gscale[s0 >> 7];
        sx = fmaf(c, (float)((short)(r & 0xFFFF)), sx);
        sy = fmaf(c, (float)(r >> 16), sy);
    }
    sx += __shfl_xor(sx, 1, 64); sy += __shfl_xor(sy, 1, 64);
    sx += __shfl_xor(sx, 2, 64); sy += __shfl_xor(sy, 2, 64);

    if (fp == 0) {
        const float2 r0 = *(const float2*)(rootacc + (size_t)n * 2);
        float a = r0.x + sx, b = r0.y + sy;
        float m = fmaxf(a, b);
        float ea = __expf(a - m), eb = __expf(b - m);
        float inv = 1.0f / (ea + eb);
        *(float2*)(out + (size_t)n * 2) = make_float2(ea * inv, eb * inv);
    }
}

// ---------------- fallback (R2 atomic path) --------------------------------
template <int Fin, int Fout, bool RELU>
__global__ void linear2_kernel(const float* __restrict__ x,
                               const float* __restrict__ Wrel,
                               const float* __restrict__ Wroot,
                               const float* __restrict__ bias,
                               float* __restrict__ t,
                               float* __restrict__ acc, int N) {
    const bool rootTask = (blockIdx.y != 0);
    const float* __restrict__ W = rootTask ? Wroot : Wrel;
    float* __restrict__ outp    = rootTask ? acc : t;

    int n = blockIdx.x * blockDim.x + threadIdx.x;
    if (n >= N) return;

    float o[Fout];
    lin_compute<Fin, Fout, RELU>(x, W, n, o);
    if (rootTask) {
#pragma unroll
        for (int f = 0; f < Fout; ++f) o[f] += bias[f];
    }
    float* op = outp + (size_t)n * Fout;
    if constexpr (Fout >= 4) {
#pragma unroll
        for (int f = 0; f < Fout; f += 4)
            *(float4*)(op + f) = make_float4(o[f], o[f + 1], o[f + 2], o[f + 3]);
    } else {
        *(float2*)op = make_float2(o[0], o[1]);
    }
}

template <int F>
__global__ void scatter_kernel(const float* __restrict__ t,
                               const int* __restrict__ src,
                               const int* __restrict__ dst,
                               float* __restrict__ acc, int nE) {
    int tid = blockIdx.x * blockDim.x + threadIdx.x;
    int e = tid / F;
    if (e >= nE) return;
    int f = tid & (F - 1);
    atomicAdd(acc + (long)dst[e] * F + f, t[(long)src[e] * F + f]);
}

__global__ void softmax2_kernel(const float* __restrict__ h, float* __restrict__ out, int N) {
    int n = blockIdx.x * blockDim.x + threadIdx.x;
    if (n >= N) return;
    float a = h[2 * n], b = h[2 * n + 1];
    float m = fmaxf(a, b);
    float ea = __expf(a - m), eb = __expf(b - m);
    float inv = 1.0f / (ea + eb);
    out[2 * n] = ea * inv;
    out[2 * n + 1] = eb * inv;
}

extern "C" void kernel_launch(void* const* d_in, const int* in_sizes, int n_in,
                              void* d_out, int out_size, void* d_ws, size_t ws_size,
                              hipStream_t stream) {
    const float* z      = (const float*)d_in[0];
    const int*   ei     = (const int*)d_in[1];
    const float* Wrel1  = (const float*)d_in[2];
    const float* Wroot1 = (const float*)d_in[3];
    const float* b1     = (const float*)d_in[4];
    const float* Wrel2  = (const float*)d_in[5];
    const float* Wroot2 = (const float*)d_in[6];
    const float* b2     = (const float*)d_in[7];
    const float* Wrel3  = (const float*)d_in[8];
    const float* Wroot3 = (const float*)d_in[9];
    const float* b3     = (const float*)d_in[10];

    const int N  = in_sizes[0] / 64;   // 100000
    const int nE = in_sizes[1] / 2;    // 1600000
    const int* src = ei;
    const int* dst = ei + nE;
    const int NB = (N + RNODES - 1) / RNODES;   // 782
    const int C  = (nE + CH - 1) / CH;          // 196 chunks

    // ---- flat workspace layout (no aliasing) ----
    char* wsb = (char*)d_ws;
    size_t off = 0;
    auto take = [&](size_t bytes) -> void* {
        void* p = (void*)(wsb + off);
        off = (off + bytes + 255) & ~(size_t)255;
        return p;
    };
    int*          chunkhist   = (int*)take((size_t)CMAX * NB_MAX * 4);
    int*          gtotal      = (int*)take((size_t)NB_MAX * 4);
    int*          bptr        = (int*)take((size_t)(NB_MAX + 1) * 4);
    unsigned int* records     = (unsigned int*)take((size_t)nE * 4);
    int*          rowptr      = (int*)take((size_t)(N + 1) * 4);
    int*          srcs_sorted = (int*)take((size_t)nE * 4);
    short*        t1          = (short*)take((size_t)N * 32 * 2);   // 64B rows
    float*        gs1         = (float*)take((size_t)NB_MAX * 4);   // 3KB
    float*        h1          = (float*)take((size_t)N * 32 * 4);
    short*        t2          = (short*)take((size_t)N * 16 * 2);   // 32B rows, 3.2MB
    float*        gs2         = (float*)take((size_t)NB_MAX * 4);
    float*        h2          = (float*)take((size_t)N * 16 * 4);
    short*        t3          = (short*)take((size_t)N * 2 * 2);    // 4B rows, 0.4MB
    float*        gs3         = (float*)take((size_t)NB_MAX * 4);
    float*        h3          = (float*)take((size_t)N * 2 * 4);
    const size_t needed = off;

    const int B = 256;
    const int nodeBlocks = (N + B - 1) / B;
    const dim3 linGrid(nodeBlocks, 2);       // y=0: rel(quant)->t, y=1: root+b->acc
    const bool packOK = (N <= (1 << 17)) && (NB <= NB_MAX) && (C <= CMAX);

    if (ws_size >= needed && packOK) {
        // ---- build: zero-global-atomic deterministic CSR (tuned params) ----
        hist_chunked_kernel<<<C, 512, 0, stream>>>(dst, chunkhist, nE, NB);
        scan_chunkhist_kernel<<<NB, CMAX, 0, stream>>>(chunkhist, gtotal, C, NB);
        scan_buckets_kernel<<<1, NB_MAX, 0, stream>>>(gtotal, bptr, NB, nE);
        bucketize_det_kernel<<<C, 512, 0, stream>>>(src, dst, chunkhist, bptr, records, nE, NB);
        place_merge_kernel<<<NB, 1024, 0, stream>>>(records, bptr, rowptr, srcs_sorted, N, nE, NB);

        // ---- Layer 1: 64 -> 32 ----
        linear_qg_kernel<64, 32, false><<<linGrid, B, 0, stream>>>(
            z, Wrel1, Wroot1, b1, t1, gs1, h1, N);
        gather32_g_kernel<<<((size_t)N * 16 + B - 1) / B, B, 0, stream>>>(
            t1, gs1, rowptr, srcs_sorted, h1, h1, N);

        // ---- Layer 2: 32 -> 16 ----
        linear_qg_kernel<32, 16, true><<<linGrid, B, 0, stream>>>(
            h1, Wrel2, Wroot2, b2, t2, gs2, h2, N);
        gather16_g_kernel<<<((size_t)N * 8 + B - 1) / B, B, 0, stream>>>(
            t2, gs2, rowptr, srcs_sorted, h2, h2, N);

        // ---- Layer 3: 16 -> 2, softmax fused ----
        linear_qg_kernel<16, 2, true><<<linGrid, B, 0, stream>>>(
            h2, Wrel3, Wroot3, b3, t3, gs3, h3, N);
        gather2_g_kernel<<<((size_t)N * 4 + B - 1) / B, B, 0, stream>>>(
            t3, gs3, rowptr, srcs_sorted, h3, (float*)d_out, N);
    } else {
        // ---- fallback: R2 atomic-scatter path (all f32, ping-pong layout) ----
        float* regionA = (float*)d_ws;
        float* regionB = regionA + (size_t)N * 32;
        float* ft1 = regionA;
        float* fh1 = regionB;
        float* ft2 = regionA;
        float* fh2 = regionA + (size_t)N * 16;
        float* ft3 = regionB;
        float* fh3 = regionB + (size_t)N * 2;
        linear2_kernel<64, 32, false><<<linGrid, B, 0, stream>>>(z, Wrel1, Wroot1, b1, ft1, fh1, N);
        scatter_kernel<32><<<((size_t)nE * 32 + B - 1) / B, B, 0, stream>>>(ft1, src, dst, fh1, nE);
        linear2_kernel<32, 16, true><<<linGrid, B, 0, stream>>>(fh1, Wrel2, Wroot2, b2, ft2, fh2, N);
        scatter_kernel<16><<<((size_t)nE * 16 + B - 1) / B, B, 0, stream>>>(ft2, src, dst, fh2, nE);
        linear2_kernel<16, 2, true><<<linGrid, B, 0, stream>>>(fh2, Wrel3, Wroot3, b3, ft3, fh3, N);
        scatter_kernel<2><<<((size_t)nE * 2 + B - 1) / B, B, 0, stream>>>(ft3, src, dst, fh3, nE);
        softmax2_kernel<<<nodeBlocks, B, 0, stream>>>(fh3, (float*)d_out, N);
    }
}